// Round 7
// baseline (90.942 us; speedup 1.0000x reference)
//
#include <hip/hip_runtime.h>
#include <hip/hip_bf16.h>
#include <stdint.h>

typedef int i32x4 __attribute__((ext_vector_type(4)));

constexpr int IN_F = 1024;
constexpr int OUT_F = 1024;
constexpr int M_TOT = 8 * 4096;   // 32768 tokens
constexpr int K_TOT = IN_F;
constexpr int N_TOT = OUT_F;

// ---------------- kernel 1: per-token int8 fake-quant -> int8 q ----------------
__global__ __launch_bounds__(256) void quant_kernel(
    const float* __restrict__ x,
    const float* __restrict__ wscale,
    int8_t* __restrict__ q,            // [M_TOT][K_TOT] int8
    float* __restrict__ inv_row)       // [M_TOT]  (= a/127 * weight_scale)
{
    const int row = blockIdx.x;
    const int t = threadIdx.x;
    const float4 v = reinterpret_cast<const float4*>(x + (size_t)row * IN_F)[t];
    float m = fmaxf(fmaxf(fabsf(v.x), fabsf(v.y)), fmaxf(fabsf(v.z), fabsf(v.w)));
    #pragma unroll
    for (int off = 32; off > 0; off >>= 1)
        m = fmaxf(m, __shfl_xor(m, off));
    __shared__ float smax[4];
    if ((t & 63) == 0) smax[t >> 6] = m;
    __syncthreads();
    m = fmaxf(fmaxf(smax[0], smax[1]), fmaxf(smax[2], smax[3]));
    const float a = fmaxf(m, 1e-5f);
    const float as = 127.0f / a;

    char4 o;
    o.x = (char)(int)fminf(fmaxf(rintf(v.x * as), -128.0f), 127.0f);
    o.y = (char)(int)fminf(fmaxf(rintf(v.y * as), -128.0f), 127.0f);
    o.z = (char)(int)fminf(fmaxf(rintf(v.z * as), -128.0f), 127.0f);
    o.w = (char)(int)fminf(fmaxf(rintf(v.w * as), -128.0f), 127.0f);
    reinterpret_cast<char4*>(q + (size_t)row * IN_F)[t] = o;
    if (t == 0) inv_row[row] = (a / 127.0f) * wscale[0];
}

// ---------------- kernel 2: unpack ternary weights (bit-plane permuted) -> int8 ----------------
__global__ __launch_bounds__(256) void unpack_kernel(
    const int* __restrict__ packed,
    int8_t* __restrict__ wt)           // [OUT_F][IN_F] int8 in {-1,0,1} (B^T layout)
{
    const int o = blockIdx.x;
    const int k0 = threadIdx.x * 4;
    const int sh = (o >> 8) * 2;
    const int pbase = ((o & 255) << 10) + k0;
    const int4 pw = *reinterpret_cast<const int4*>(packed + pbase);
    char4 r;
    r.x = (char)(((pw.x >> sh) & 3) - 1);
    r.y = (char)(((pw.y >> sh) & 3) - 1);
    r.z = (char)(((pw.z >> sh) & 3) - 1);
    r.w = (char)(((pw.w >> sh) & 3) - 1);
    *reinterpret_cast<char4*>(wt + (size_t)o * IN_F + k0) = r;
}

// ---------------- kernel 3: int8 MFMA GEMM, 256x256, BK=128, deep prefetch ----------------
// mfma_i32_16x16x64_i8. 8 waves (2M x 4N), per-wave 128x64 output (round-5 verified
// decomposition + epilogue). 2 phases/K-tile, 32-MFMA bursts.
// Deep asymmetric prefetch: A = 3 LDS slots (staged 2 K-tiles ahead; q is L3-served),
// B = 2 slots (1 ahead; 1 MiB L2-resident weight). LDS = 160 KiB exactly.
// Issue points: P0 stages B(T+1), P1 stages A(T+2). One counted vmcnt(4)+barrier per
// K-tile at loop top (audit: only loads issued after B(T) are A(T+1)'s 4). Never 0
// mid-loop. T2 swizzle: linear LDS dest, inverse-swizzled global src, swizzled ds_read
// (proven 0-conflict at BK=128).
constexpr int BM = 256, BN = 256, BK = 128;
constexpr int NT = K_TOT / BK;   // 8

__global__ __launch_bounds__(512, 2) void gemm_kernel(
    const int8_t* __restrict__ qa,     // [M_TOT][K_TOT] int8
    const int8_t* __restrict__ wb,     // [N_TOT][K_TOT] int8
    const float* __restrict__ inv_row,
    const float* __restrict__ bias,
    float* __restrict__ out)
{
    // XCD-aware swizzle: nwg = 512, divisible by 8 -> bijective simple remap
    int bid = blockIdx.x;
    bid = (bid & 7) * ((int)gridDim.x >> 3) + (bid >> 3);
    const int tm = bid >> 2;            // 0..127
    const int tn = bid & 3;             // 0..3

    const int tid = threadIdx.x;
    const int lane = tid & 63;
    const int wid = tid >> 6;           // 0..7
    const int wr = wid >> 2;            // 0..1 (M half: rows wr*128..)
    const int wc = wid & 3;             // 0..3 (N quarter: cols wc*64..)

    __shared__ int8_t ldsA[3][2][128 * 128];  // 3 slots x 2 regions(128 rows) = 96 KiB
    __shared__ int8_t ldsB[2][2][128 * 128];  // 2 slots x 2 regions(128 cols) = 64 KiB

    const int rowA0 = tm * BM;
    const int rowB0 = tn * BN;
    const int frow = lane & 15;
    const int fq = lane >> 4;           // 0..3

    i32x4 acc[8][4] = {};

    // stage one 16 KiB region (128 rows x 128 k): 2 global_load_lds per thread
    auto stageA = [&](int slot, int region, int kt) {
        #pragma unroll
        for (int j = 0; j < 2; ++j) {
            const int c = j * 512 + tid;          // chunk 0..1023 (16B each)
            const int rl = c >> 3, cc = c & 7;
            const int scc = cc ^ (rl & 7);        // inverse swizzle on global src
            const int8_t* src = qa + (size_t)(rowA0 + region * 128 + rl) * K_TOT
                                   + kt * BK + scc * 16;
            __builtin_amdgcn_global_load_lds(
                (const __attribute__((address_space(1))) void*)src,
                (__attribute__((address_space(3))) void*)&ldsA[slot][region][c * 16],
                16, 0, 0);
        }
    };
    auto stageB = [&](int slot, int region, int kt) {
        #pragma unroll
        for (int j = 0; j < 2; ++j) {
            const int c = j * 512 + tid;
            const int rl = c >> 3, cc = c & 7;
            const int scc = cc ^ (rl & 7);
            const int8_t* src = wb + (size_t)(rowB0 + region * 128 + rl) * K_TOT
                                   + kt * BK + scc * 16;
            __builtin_amdgcn_global_load_lds(
                (const __attribute__((address_space(1))) void*)src,
                (__attribute__((address_space(3))) void*)&ldsB[slot][region][c * 16],
                16, 0, 0);
        }
    };

    // A frag: row = wr*128 + mf*16 + frow -> region wr, local = mf*16 + frow (mf 0..7)
    auto ldA = [&](int slot, int mf, int ks) -> i32x4 {
        const int local = mf * 16 + frow;
        const int ch = (ks * 4 + fq) ^ (local & 7);
        return *reinterpret_cast<const i32x4*>(&ldsA[slot][wr][(local * 8 + ch) * 16]);
    };
    // B frag: col n = wc*64 + nf*16 + frow -> region wc>>1, local = (wc&1)*64 + nf*16 + frow
    auto ldB = [&](int slot, int nf, int ks) -> i32x4 {
        const int local = (wc & 1) * 64 + nf * 16 + frow;
        const int ch = (ks * 4 + fq) ^ (local & 7);
        return *reinterpret_cast<const i32x4*>(&ldsB[slot][wc >> 1][(local * 8 + ch) * 16]);
    };

    // prologue: A(0), B(0), A(1) -- 12 loads
    stageA(0, 0, 0); stageA(0, 1, 0);
    stageB(0, 0, 0); stageB(0, 1, 0);
    stageA(1, 0, 1); stageA(1, 1, 1);

    for (int T = 0; T < NT; ++T) {
        const int sa = T % 3, sb = T & 1;
        // certify A(T)+B(T): only loads issued after B(T) are A(T+1)'s 4
        if (T < NT - 1) asm volatile("s_waitcnt vmcnt(4)" ::: "memory");
        else            asm volatile("s_waitcnt vmcnt(0)" ::: "memory");
        __builtin_amdgcn_s_barrier();

        i32x4 aF[4][2], bF[4][2];

        // ---- P0: read B all (8) + A m0-3 (8); stage B(T+1); MFMA rows-lo (32)
        #pragma unroll
        for (int nf = 0; nf < 4; ++nf)
            #pragma unroll
            for (int ks = 0; ks < 2; ++ks)
                bF[nf][ks] = ldB(sb, nf, ks);
        #pragma unroll
        for (int mf = 0; mf < 4; ++mf)
            #pragma unroll
            for (int ks = 0; ks < 2; ++ks)
                aF[mf][ks] = ldA(sa, mf, ks);
        if (T + 1 < NT) { stageB((T + 1) & 1, 0, T + 1); stageB((T + 1) & 1, 1, T + 1); }
        __builtin_amdgcn_s_barrier();
        asm volatile("s_waitcnt lgkmcnt(0)" ::: "memory");
        __builtin_amdgcn_sched_barrier(0);
        __builtin_amdgcn_s_setprio(1);
        #pragma unroll
        for (int mf = 0; mf < 4; ++mf)
            #pragma unroll
            for (int nf = 0; nf < 4; ++nf)
                #pragma unroll
                for (int ks = 0; ks < 2; ++ks)
                    acc[mf][nf] = __builtin_amdgcn_mfma_i32_16x16x64_i8(
                        aF[mf][ks], bF[nf][ks], acc[mf][nf], 0, 0, 0);
        __builtin_amdgcn_s_setprio(0);
        __builtin_amdgcn_s_barrier();

        // ---- P1: read A m4-7 (8); stage A(T+2); MFMA rows-hi (32)
        #pragma unroll
        for (int mf = 0; mf < 4; ++mf)
            #pragma unroll
            for (int ks = 0; ks < 2; ++ks)
                aF[mf][ks] = ldA(sa, 4 + mf, ks);
        if (T + 2 < NT) { stageA((T + 2) % 3, 0, T + 2); stageA((T + 2) % 3, 1, T + 2); }
        __builtin_amdgcn_s_barrier();
        asm volatile("s_waitcnt lgkmcnt(0)" ::: "memory");
        __builtin_amdgcn_sched_barrier(0);
        __builtin_amdgcn_s_setprio(1);
        #pragma unroll
        for (int mf = 0; mf < 4; ++mf)
            #pragma unroll
            for (int nf = 0; nf < 4; ++nf)
                #pragma unroll
                for (int ks = 0; ks < 2; ++ks)
                    acc[4 + mf][nf] = __builtin_amdgcn_mfma_i32_16x16x64_i8(
                        aF[mf][ks], bF[nf][ks], acc[4 + mf][nf], 0, 0, 0);
        __builtin_amdgcn_s_setprio(0);
        // loop wraps to top vmcnt + barrier
    }

    // epilogue: C/D 16x16 layout: col = lane&15, row = fq*4 + reg. acc exact in i32.
    #pragma unroll
    for (int mi = 0; mi < 8; ++mi) {
        #pragma unroll
        for (int j = 0; j < 4; ++j) {
            const int gm = rowA0 + wr * 128 + mi * 16 + fq * 4 + j;
            const float sc = inv_row[gm];
            #pragma unroll
            for (int nf = 0; nf < 4; ++nf) {
                const int gn = rowB0 + wc * 64 + nf * 16 + frow;
                out[(size_t)gm * N_TOT + gn] = (float)acc[mi][nf][j] * sc + bias[gn];
            }
        }
    }
}

extern "C" void kernel_launch(void* const* d_in, const int* in_sizes, int n_in,
                              void* d_out, int out_size, void* d_ws, size_t ws_size,
                              hipStream_t stream) {
    const float* x = (const float*)d_in[0];
    const int* packed = (const int*)d_in[1];
    const float* wscale = (const float*)d_in[2];
    const float* bias = (const float*)d_in[3];
    float* out = (float*)d_out;

    int8_t* q = (int8_t*)d_ws;                                          // 32 MiB
    int8_t* wt = (int8_t*)((char*)d_ws + (size_t)M_TOT * K_TOT);        // 1 MiB
    float* inv_row = (float*)((char*)d_ws + (size_t)M_TOT * K_TOT + (size_t)N_TOT * K_TOT);

    quant_kernel<<<M_TOT, 256, 0, stream>>>(x, wscale, q, inv_row);
    unpack_kernel<<<OUT_F, 256, 0, stream>>>(packed, wt);
    gemm_kernel<<<(M_TOT / BM) * (N_TOT / BN), 512, 0, stream>>>(q, wt, inv_row, bias, out);
}

// Round 8
// 89.571 us; speedup vs baseline: 1.0153x; 1.0153x over previous
//
#include <hip/hip_runtime.h>
#include <hip/hip_bf16.h>
#include <stdint.h>

typedef int i32x4 __attribute__((ext_vector_type(4)));

constexpr int IN_F = 1024;
constexpr int OUT_F = 1024;
constexpr int M_TOT = 8 * 4096;   // 32768 tokens
constexpr int K_TOT = IN_F;
constexpr int N_TOT = OUT_F;

// ---------------- kernel 1: per-token int8 fake-quant -> int8 q ----------------
__global__ __launch_bounds__(256) void quant_kernel(
    const float* __restrict__ x,
    const float* __restrict__ wscale,
    int8_t* __restrict__ q,            // [M_TOT][K_TOT] int8
    float* __restrict__ inv_row)       // [M_TOT]  (= a/127 * weight_scale)
{
    const int row = blockIdx.x;
    const int t = threadIdx.x;
    const float4 v = reinterpret_cast<const float4*>(x + (size_t)row * IN_F)[t];
    float m = fmaxf(fmaxf(fabsf(v.x), fabsf(v.y)), fmaxf(fabsf(v.z), fabsf(v.w)));
    #pragma unroll
    for (int off = 32; off > 0; off >>= 1)
        m = fmaxf(m, __shfl_xor(m, off));
    __shared__ float smax[4];
    if ((t & 63) == 0) smax[t >> 6] = m;
    __syncthreads();
    m = fmaxf(fmaxf(smax[0], smax[1]), fmaxf(smax[2], smax[3]));
    const float a = fmaxf(m, 1e-5f);
    const float as = 127.0f / a;

    char4 o;
    o.x = (char)(int)fminf(fmaxf(rintf(v.x * as), -128.0f), 127.0f);
    o.y = (char)(int)fminf(fmaxf(rintf(v.y * as), -128.0f), 127.0f);
    o.z = (char)(int)fminf(fmaxf(rintf(v.z * as), -128.0f), 127.0f);
    o.w = (char)(int)fminf(fmaxf(rintf(v.w * as), -128.0f), 127.0f);
    reinterpret_cast<char4*>(q + (size_t)row * IN_F)[t] = o;
    if (t == 0) inv_row[row] = (a / 127.0f) * wscale[0];
}

// ---------------- kernel 2: unpack ternary weights (bit-plane permuted) -> int8 ----------------
__global__ __launch_bounds__(256) void unpack_kernel(
    const int* __restrict__ packed,
    int8_t* __restrict__ wt)           // [OUT_F][IN_F] int8 in {-1,0,1} (B^T layout)
{
    const int o = blockIdx.x;
    const int k0 = threadIdx.x * 4;
    const int sh = (o >> 8) * 2;
    const int pbase = ((o & 255) << 10) + k0;
    const int4 pw = *reinterpret_cast<const int4*>(packed + pbase);
    char4 r;
    r.x = (char)(((pw.x >> sh) & 3) - 1);
    r.y = (char)(((pw.y >> sh) & 3) - 1);
    r.z = (char)(((pw.z >> sh) & 3) - 1);
    r.w = (char)(((pw.w >> sh) & 3) - 1);
    *reinterpret_cast<char4*>(wt + (size_t)o * IN_F + k0) = r;
}

// ---------------- kernel 3: int8 MFMA GEMM, BM=256 x BN=128, BK=64, 2 blocks/CU ----------------
// mfma_i32_16x16x64_i8 (one MFMA = full BK). 8 waves (4M x 2N), per-wave 64x64 output.
// LDS 72 KiB = A 3 slots x 16 KiB + B 3 slots x 8 KiB -> 2 blocks/CU (16 waves, 4/SIMD),
// __launch_bounds__(512,4) caps VGPR at 128 (est ~110, no spill).
// Per K-tile: ONE barrier + ONE counted vmcnt: tile T staged at iter T-2 (2-tile
// lookahead); at top of T outstanding = {T:3, T+1:3} -> vmcnt(3) certifies T.
// Slot (T+2)%3 re-staged in T was last read in T-1; every wave drains its own
// ds_reads (lgkmcnt(0)) before the top barrier -> safe.
// Swizzle (BK=64 -> 4 chunks/row): ch ^= (row>>1)&3 -> 2-way bank access (free);
// same involution on global source (j-invariant per thread), linear LDS dest.
constexpr int BM = 256, BN = 128, BK = 64;
constexpr int NT = K_TOT / BK;   // 16

__global__ __launch_bounds__(512, 4) void gemm_kernel(
    const int8_t* __restrict__ qa,     // [M_TOT][K_TOT] int8
    const int8_t* __restrict__ wb,     // [N_TOT][K_TOT] int8
    const float* __restrict__ inv_row,
    const float* __restrict__ bias,
    float* __restrict__ out)
{
    // XCD-aware swizzle: nwg = 1024, divisible by 8 -> bijective simple remap
    int bid = blockIdx.x;
    bid = (bid & 7) * ((int)gridDim.x >> 3) + (bid >> 3);
    const int tm = bid >> 3;            // 0..127
    const int tn = bid & 7;             // 0..7

    const int tid = threadIdx.x;
    const int lane = tid & 63;
    const int wid = tid >> 6;           // 0..7
    const int wr = wid >> 1;            // 0..3 (M quarter: rows wr*64..)
    const int wc = wid & 1;             // 0..1 (N half: cols wc*64..)

    __shared__ int8_t ldsA[3 * 256 * 64];   // 48 KiB
    __shared__ int8_t ldsB[3 * 128 * 64];   // 24 KiB

    const int rowA0 = tm * BM;
    const int rowB0 = tn * BN;
    const int frow = lane & 15;
    const int fq = lane >> 4;           // 0..3

    i32x4 acc[4][4] = {};

    // per-thread staging constants: chunk c = j*512 + tid; rl = c>>2 = j*128 + (tid>>2);
    // cc = tid&3; swizzled source chunk scc = cc ^ ((rl>>1)&3) = cc ^ (((tid>>2)>>1)&3)
    // (j*128 contributes 0 to bits 1..2 after >>1 &3) -> j-invariant.
    const int r0 = tid >> 2;
    const int scc0 = (tid & 3) ^ ((r0 >> 1) & 3);
    const int8_t* srcA0 = qa + (size_t)(rowA0 + r0) * K_TOT + scc0 * 16;
    const int8_t* srcB0 = wb + (size_t)(rowB0 + r0) * K_TOT + scc0 * 16;
    const int dA0 = tid * 16, dA1 = (512 + tid) * 16;   // LDS byte offsets within slot

    // stage tile kt: A = 2 loads (rows r0, 128+r0), B = 1 load. 3 loads, fixed order.
    auto stage = [&](int slot, int kt) {
        __builtin_amdgcn_global_load_lds(
            (const __attribute__((address_space(1))) void*)(srcA0 + kt * BK),
            (__attribute__((address_space(3))) void*)&ldsA[slot * 16384 + dA0], 16, 0, 0);
        __builtin_amdgcn_global_load_lds(
            (const __attribute__((address_space(1))) void*)(srcA0 + (size_t)128 * K_TOT + kt * BK),
            (__attribute__((address_space(3))) void*)&ldsA[slot * 16384 + dA1], 16, 0, 0);
        __builtin_amdgcn_global_load_lds(
            (const __attribute__((address_space(1))) void*)(srcB0 + kt * BK),
            (__attribute__((address_space(3))) void*)&ldsB[slot * 8192 + dA0], 16, 0, 0);
    };

    auto ldA = [&](int slot, int mf) -> i32x4 {
        const int r = wr * 64 + mf * 16 + frow;
        const int ch = fq ^ ((r >> 1) & 3);
        return *reinterpret_cast<const i32x4*>(&ldsA[slot * 16384 + r * 64 + ch * 16]);
    };
    auto ldB = [&](int slot, int nf) -> i32x4 {
        const int r = wc * 64 + nf * 16 + frow;
        const int ch = fq ^ ((r >> 1) & 3);
        return *reinterpret_cast<const i32x4*>(&ldsB[slot * 8192 + r * 64 + ch * 16]);
    };

    // prologue: tiles 0,1 (6 loads; oldest 3 = tile 0)
    stage(0, 0);
    stage(1, 1);

    int sCur = 0;
    for (int T = 0; T < NT; ++T) {
        const int s = sCur;
        const int s2 = (sCur + 2 >= 3) ? sCur - 1 : sCur + 2;   // (T+2)%3

        if (T < NT - 1) asm volatile("s_waitcnt vmcnt(3)" ::: "memory");
        else            asm volatile("s_waitcnt vmcnt(0)" ::: "memory");
        __builtin_amdgcn_s_barrier();

        i32x4 aF[4], bF[4];
        #pragma unroll
        for (int mf = 0; mf < 4; ++mf) aF[mf] = ldA(s, mf);
        #pragma unroll
        for (int nf = 0; nf < 4; ++nf) bF[nf] = ldB(s, nf);

        if (T + 2 < NT) stage(s2, T + 2);

        asm volatile("s_waitcnt lgkmcnt(0)" ::: "memory");
        __builtin_amdgcn_sched_barrier(0);
        __builtin_amdgcn_s_setprio(1);
        #pragma unroll
        for (int mf = 0; mf < 4; ++mf)
            #pragma unroll
            for (int nf = 0; nf < 4; ++nf)
                acc[mf][nf] = __builtin_amdgcn_mfma_i32_16x16x64_i8(
                    aF[mf], bF[nf], acc[mf][nf], 0, 0, 0);
        __builtin_amdgcn_s_setprio(0);

        sCur = (sCur + 1 >= 3) ? 0 : sCur + 1;
    }

    // epilogue: C/D 16x16 layout: col = lane&15, row = fq*4 + reg. acc exact in i32.
    #pragma unroll
    for (int mf = 0; mf < 4; ++mf) {
        #pragma unroll
        for (int j = 0; j < 4; ++j) {
            const int gm = rowA0 + wr * 64 + mf * 16 + fq * 4 + j;
            const float sc = inv_row[gm];
            #pragma unroll
            for (int nf = 0; nf < 4; ++nf) {
                const int gn = rowB0 + wc * 64 + nf * 16 + frow;
                out[(size_t)gm * N_TOT + gn] = (float)acc[mf][nf][j] * sc + bias[gn];
            }
        }
    }
}

extern "C" void kernel_launch(void* const* d_in, const int* in_sizes, int n_in,
                              void* d_out, int out_size, void* d_ws, size_t ws_size,
                              hipStream_t stream) {
    const float* x = (const float*)d_in[0];
    const int* packed = (const int*)d_in[1];
    const float* wscale = (const float*)d_in[2];
    const float* bias = (const float*)d_in[3];
    float* out = (float*)d_out;

    int8_t* q = (int8_t*)d_ws;                                          // 32 MiB
    int8_t* wt = (int8_t*)((char*)d_ws + (size_t)M_TOT * K_TOT);        // 1 MiB
    float* inv_row = (float*)((char*)d_ws + (size_t)M_TOT * K_TOT + (size_t)N_TOT * K_TOT);

    quant_kernel<<<M_TOT, 256, 0, stream>>>(x, wscale, q, inv_row);
    unpack_kernel<<<OUT_F, 256, 0, stream>>>(packed, wt);
    gemm_kernel<<<(M_TOT / BM) * (N_TOT / BN), 512, 0, stream>>>(q, wt, inv_row, bias, out);
}